// Round 1
// baseline (1673.774 us; speedup 1.0000x reference)
//
#include <hip/hip_runtime.h>

#define NUSERS 100000
#define NITEMS 50000
#define NN (NUSERS + NITEMS)          // 150000 nodes
#define D 64
#define NE 6400000
#define QB 1024
#define RS_PAD 150016                  // padded row_start length

// ---------------------------------------------------------------------------
// init: x0 = acc = concat(user_emb, item_emb), as float4
// ---------------------------------------------------------------------------
__global__ void init_kernel(const float4* __restrict__ ue, const float4* __restrict__ ie,
                            float4* __restrict__ x0, float4* __restrict__ acc) {
    const int USER4 = NUSERS * (D / 4);     // 1.6M
    const int TOT4  = NN * (D / 4);         // 2.4M
    for (int i = blockIdx.x * blockDim.x + threadIdx.x; i < TOT4;
         i += gridDim.x * blockDim.x) {
        float4 v = (i < USER4) ? ue[i] : ie[i - USER4];
        x0[i]  = v;
        acc[i] = v;
    }
}

__global__ void zero_kernel(int* __restrict__ p, int n) {
    for (int i = blockIdx.x * blockDim.x + threadIdx.x; i < n;
         i += gridDim.x * blockDim.x)
        p[i] = 0;
}

__global__ void hist_kernel(const int* __restrict__ dst, int* __restrict__ cnt, int n) {
    for (int i = blockIdx.x * blockDim.x + threadIdx.x; i < n;
         i += gridDim.x * blockDim.x)
        atomicAdd(&cnt[dst[i]], 1);
}

// ---------------------------------------------------------------------------
// single-block exclusive scan over cnt[0..nn) -> row_start, cursor (4 elems/thread)
// ---------------------------------------------------------------------------
__global__ __launch_bounds__(1024) void scan_kernel(int* __restrict__ cnt,
                                                    int* __restrict__ row_start, int nn) {
    __shared__ int wbase[16];
    __shared__ int s_carry;
    __shared__ int s_tot;
    const int t = threadIdx.x;
    const int lane = t & 63;
    const int wid = t >> 6;
    if (t == 0) s_carry = 0;
    __syncthreads();
    for (int chunk = 0; chunk < nn; chunk += 4096) {
        const int i0 = chunk + t * 4;
        int c0 = 0, c1 = 0, c2 = 0, c3 = 0;
        if (i0 + 3 < nn) {
            int4 c = *reinterpret_cast<const int4*>(cnt + i0);
            c0 = c.x; c1 = c.y; c2 = c.z; c3 = c.w;
        } else {
            if (i0 + 0 < nn) c0 = cnt[i0 + 0];
            if (i0 + 1 < nn) c1 = cnt[i0 + 1];
            if (i0 + 2 < nn) c2 = cnt[i0 + 2];
            if (i0 + 3 < nn) c3 = cnt[i0 + 3];
        }
        const int v = c0 + c1 + c2 + c3;
        // inclusive wave scan of v
        int s = v;
#pragma unroll
        for (int off = 1; off < 64; off <<= 1) {
            int y = __shfl_up(s, off, 64);
            if (lane >= off) s += y;
        }
        if (lane == 63) wbase[wid] = s;
        __syncthreads();
        if (t < 16) {
            int w = wbase[t];
            int ss = w;
#pragma unroll
            for (int off = 1; off < 16; off <<= 1) {
                int y = __shfl_up(ss, off, 16);
                if (t >= off) ss += y;
            }
            wbase[t] = ss - w;
            if (t == 15) s_tot = ss;
        }
        __syncthreads();
        const int base = s_carry;
        int e0 = base + wbase[wid] + (s - v);
        int e1 = e0 + c0;
        int e2 = e1 + c1;
        int e3 = e2 + c2;
        if (i0 + 0 < nn) { row_start[i0 + 0] = e0; cnt[i0 + 0] = e0; }
        if (i0 + 1 < nn) { row_start[i0 + 1] = e1; cnt[i0 + 1] = e1; }
        if (i0 + 2 < nn) { row_start[i0 + 2] = e2; cnt[i0 + 2] = e2; }
        if (i0 + 3 < nn) { row_start[i0 + 3] = e3; cnt[i0 + 3] = e3; }
        __syncthreads();
        if (t == 0) s_carry = base + s_tot;
        __syncthreads();
    }
    if (t == 0) row_start[nn] = s_carry;
}

__global__ void scatter_kernel(const int* __restrict__ src, const int* __restrict__ dst,
                               const float* __restrict__ val, int* __restrict__ cursor,
                               int* __restrict__ ssrc, float* __restrict__ sval, int n) {
    for (int i = blockIdx.x * blockDim.x + threadIdx.x; i < n;
         i += gridDim.x * blockDim.x) {
        int d = dst[i];
        int pos = atomicAdd(&cursor[d], 1);
        ssrc[pos] = src[i];
        sval[pos] = val[i];
    }
}

// ---------------------------------------------------------------------------
// SpMM: one wave per dst row, lane = dim. xout[r] = sum val*x[src]; acc += xout
// ---------------------------------------------------------------------------
__global__ __launch_bounds__(256) void spmm_kernel(const float* __restrict__ x,
                                                   float* __restrict__ xout,
                                                   float* __restrict__ acc,
                                                   const int* __restrict__ row_start,
                                                   const int* __restrict__ ssrc,
                                                   const float* __restrict__ sval,
                                                   int nn) {
    int wave = (blockIdx.x << 2) | (threadIdx.x >> 6);
    int row = __builtin_amdgcn_readfirstlane(wave);
    if (row >= nn) return;
    const int lane = threadIdx.x & 63;
    int b = row_start[row];
    int e = row_start[row + 1];
    float a = 0.f;
    int i = b;
    for (; i + 2 <= e; i += 2) {
        int s0 = ssrc[i];
        int s1 = ssrc[i + 1];
        float v0 = sval[i];
        float v1 = sval[i + 1];
        a = fmaf(v0, x[(size_t)s0 * D + lane], a);
        a = fmaf(v1, x[(size_t)s1 * D + lane], a);
    }
    if (i < e) a = fmaf(sval[i], x[(size_t)ssrc[i] * D + lane], a);
    size_t o = (size_t)row * D + lane;
    xout[o] = a;
    acc[o] += a;
}

// copy item part of acc into ws (so the rating kernel never reads d_out)
__global__ void copy_items_kernel(const float4* __restrict__ acc4, float4* __restrict__ items4) {
    const int TOT4 = NITEMS * (D / 4);      // 800000
    const int BASE4 = NUSERS * (D / 4);
    for (int i = blockIdx.x * blockDim.x + threadIdx.x; i < TOT4;
         i += gridDim.x * blockDim.x)
        items4[i] = acc4[BASE4 + i];
}

// gather queried users, fold the two /4 layer-means into one 1/16 scale
__global__ void ug_kernel(const float4* __restrict__ acc4, const int* __restrict__ users,
                          float4* __restrict__ ug4) {
    int i = blockIdx.x * blockDim.x + threadIdx.x;   // [0, QB*16)
    if (i >= QB * (D / 4)) return;
    int b = i >> 4;
    int k = i & 15;
    float4 v = acc4[(size_t)users[b] * (D / 4) + k];
    const float sc = 1.0f / 16.0f;
    ug4[i] = make_float4(v.x * sc, v.y * sc, v.z * sc, v.w * sc);
}

// ---------------------------------------------------------------------------
// rating: out[u][i] = sigmoid(dot(ug[u], item[i])). item row in 16xfloat4 regs,
// 8-user register tile, user loads are wave-uniform -> scalar loads.
// ---------------------------------------------------------------------------
__global__ __launch_bounds__(256) void rating_kernel(const float* __restrict__ items_s,
                                                     const float* __restrict__ ug,
                                                     float* __restrict__ out) {
    const int i = blockIdx.x * 256 + threadIdx.x;
    const bool valid = i < NITEMS;
    const int ic = valid ? i : 0;
    float4 ir[16];
    const float4* irow = reinterpret_cast<const float4*>(items_s) + (size_t)ic * (D / 4);
#pragma unroll
    for (int k = 0; k < 16; ++k) ir[k] = irow[k];
    const float4* ug4 = reinterpret_cast<const float4*>(ug);
    const int u0 = blockIdx.y * 128;
    for (int g = 0; g < 16; ++g) {
        const int ub = u0 + g * 8;
        float s[8];
#pragma unroll
        for (int j = 0; j < 8; ++j) s[j] = 0.f;
#pragma unroll
        for (int k = 0; k < 16; ++k) {
            const float4 iv = ir[k];
#pragma unroll
            for (int j = 0; j < 8; ++j) {
                const float4 uv = ug4[(ub + j) * (D / 4) + k];
                s[j] = fmaf(iv.x, uv.x, s[j]);
                s[j] = fmaf(iv.y, uv.y, s[j]);
                s[j] = fmaf(iv.z, uv.z, s[j]);
                s[j] = fmaf(iv.w, uv.w, s[j]);
            }
        }
        if (valid) {
#pragma unroll
            for (int j = 0; j < 8; ++j) {
                float r = 1.0f / (1.0f + __expf(-s[j]));
                out[(size_t)(ub + j) * NITEMS + i] = r;
            }
        }
    }
}

extern "C" void kernel_launch(void* const* d_in, const int* in_sizes, int n_in,
                              void* d_out, int out_size, void* d_ws, size_t ws_size,
                              hipStream_t stream) {
    const float* user_emb = (const float*)d_in[0];
    const float* item_emb = (const float*)d_in[1];
    const float* edge_val = (const float*)d_in[2];
    const int*   edge_src = (const int*)d_in[3];
    const int*   edge_dst = (const int*)d_in[4];
    const int*   users    = (const int*)d_in[5];

    // d_out (51.2M floats) doubles as scratch; rating_kernel rewrites all of it
    // and reads only from d_ws.
    float* ob  = (float*)d_out;
    float* x0  = ob;                                   //  9.6M f
    float* x1  = x0 + (size_t)NN * D;                  //  9.6M f
    float* acc = x1 + (size_t)NN * D;                  //  9.6M f
    int*   ssrc = (int*)(acc + (size_t)NN * D);        //  6.4M i
    float* sval = (float*)(ssrc + NE);                 //  6.4M f
    int*   row_start = (int*)(sval + NE);              //  NN+1 (padded)
    int*   cursor    = row_start + RS_PAD;             //  NN
    // total: 41.9M floats < 51.2M

    // d_ws: only what rating_kernel reads (~13.1 MB)
    float* items_s = (float*)d_ws;                     // NITEMS*D
    float* ug      = items_s + (size_t)NITEMS * D;     // QB*D

    init_kernel<<<2048, 256, 0, stream>>>((const float4*)user_emb, (const float4*)item_emb,
                                          (float4*)x0, (float4*)acc);
    zero_kernel<<<256, 256, 0, stream>>>(cursor, NN);
    hist_kernel<<<2048, 256, 0, stream>>>(edge_dst, cursor, NE);
    scan_kernel<<<1, 1024, 0, stream>>>(cursor, row_start, NN);
    scatter_kernel<<<2048, 256, 0, stream>>>(edge_src, edge_dst, edge_val, cursor,
                                             ssrc, sval, NE);
    // 3 propagation layers (wave per row): 150000 rows / 4 waves per block
    spmm_kernel<<<37500, 256, 0, stream>>>(x0, x1, acc, row_start, ssrc, sval, NN);
    spmm_kernel<<<37500, 256, 0, stream>>>(x1, x0, acc, row_start, ssrc, sval, NN);
    spmm_kernel<<<37500, 256, 0, stream>>>(x0, x1, acc, row_start, ssrc, sval, NN);

    copy_items_kernel<<<1024, 256, 0, stream>>>((const float4*)acc, (float4*)items_s);
    ug_kernel<<<64, 256, 0, stream>>>((const float4*)acc, users, (float4*)ug);

    rating_kernel<<<dim3((NITEMS + 255) / 256, QB / 128), 256, 0, stream>>>(items_s, ug, ob);
}